// Round 15
// baseline (122.220 us; speedup 1.0000x reference)
//
#include <hip/hip_runtime.h>

typedef _Float16 half_t;
typedef __fp16   fp16x2 __attribute__((ext_vector_type(2)));
typedef _Float16 half4_t __attribute__((ext_vector_type(4)));
typedef _Float16 half8   __attribute__((ext_vector_type(8)));
typedef float    f32x4   __attribute__((ext_vector_type(4)));
typedef unsigned short u16x8 __attribute__((ext_vector_type(8)));

#define KP_S    0.057735026918962574f  // 0.1/sqrt(3)
#define INV_EXT 11.547005383792515f    // 1/(0.05*sqrt(3))
#define GPITCH  1824                   // half-G row: 32ch*28l*2B=1792 + 32 pad (mod128=32)
#define NBLK    768                    // persistent blocks = 3/CU (512 thr, 24 waves/CU)
#define NTILE   2500                   // 40000 queries / 16 per tile
#define WT_BYTES (64 * 1792 * 2)       // 229376
#define XH_BYTES (40000 * 64 * 2)      // 5120000

union H8 { half8 v; fp16x2 h2[4]; };
union H4 { half4_t v; fp16x2 h2[2]; };

// LDS-visibility-only barrier: no vmcnt drain (gathers/out-stores stay in flight).
#define BAR_LGKM() do {                                                        \
    __asm__ volatile("s_waitcnt lgkmcnt(0)\n\ts_barrier" ::: "memory");        \
    __builtin_amdgcn_sched_barrier(0);                                         \
} while (0)

// WT[o][k], k = i*28 + l (fp16); l==27 zero pad mirrors G's pitch-28 layout.
// Channel permutation c = 4*(i&15) + (i>>4): MFMA column (nt,lr) holds x-channel
// 4*lr+nt so the phase-C gather is one 8B fp16 load per lane per row.
__global__ void build_wt(const float* __restrict__ W, half_t* __restrict__ WT) {
    int t = blockIdx.x * 256 + threadIdx.x;       // 64*1792 = 114688 exact
    if (t >= 64 * 1792) return;
    int o = t / 1792, k = t - o * 1792;
    int i = k / 28,   l = k - i * 28;
    int c = 4 * (i & 15) + (i >> 4);              // permuted channel index
    WT[t] = (l < 27) ? (half_t)W[(l * 64 + c) * 64 + o] : (half_t)0.f;
}

// x (f32, [40000][64]) -> xh (fp16, same layout): 128 B/row = 1 cache line
__global__ void build_xh(const float* __restrict__ x, half_t* __restrict__ xh) {
    int t = blockIdx.x * 256 + threadIdx.x;       // 2500*256 = 640000 exact
    f32x4 v = *(const f32x4*)(x + t * 4);
    H4 h;
    h.h2[0] = __builtin_amdgcn_cvt_pkrtz(v.x, v.y);
    h.h2[1] = __builtin_amdgcn_cvt_pkrtz(v.z, v.w);
    *(half4_t*)(xh + t * 4) = h.v;
}

// issue one query's x-gather into 8 half4 regs (16 VGPR)
#define ISSUE_XV1(BUF, Q, XV) do {                                             \
    u16x8 id8 = *(const u16x8*)&idx_lds[BUF][Q][8 * g];                        \
    _Pragma("unroll")                                                          \
    for (int j = 0; j < 8; ++j) {                                              \
        if constexpr (XHALF) {                                                 \
            XV[j] = *(const half4_t*)(xh + (int)id8[j] * 64 + 4 * lr);         \
        } else {                                                               \
            f32x4 t4 = *(const f32x4*)(x + (int)id8[j] * 64 + 4 * lr);         \
            H4 hh;                                                             \
            hh.h2[0] = __builtin_amdgcn_cvt_pkrtz(t4.x, t4.y);                 \
            hh.h2[1] = __builtin_amdgcn_cvt_pkrtz(t4.z, t4.w);                 \
            XV[j] = hh.v;                                                      \
        }                                                                      \
    }                                                                          \
} while (0)

// per-lane influence weights for one query -> packed A-fragments (held, reused)
#define COMP_W(Q, CUR, A0, A1) do {                                            \
    float w0v[8], w1v[8];                                                      \
    _Pragma("unroll")                                                          \
    for (int j = 0; j < 8; ++j) {                                              \
        half4_t nb = nbr_lds[CUR][Q][8 * g + j];                               \
        float nx = (float)nb[0], ny = (float)nb[1], nz = (float)nb[2];         \
        float dx = nx - kx0, dy = ny - ky0, dz = nz - kz0;                     \
        w0v[j] = fmaxf(fmaf(__builtin_amdgcn_sqrtf(dx*dx + dy*dy + dz*dz), -INV_EXT, 1.f), 0.f); \
        float ex = nx - kx1, ey = ny - ky1, ez = nz - kz1;                     \
        w1v[j] = fmaxf(fmaf(__builtin_amdgcn_sqrtf(ex*ex + ey*ey + ez*ez), -INV_EXT, cbias), 0.f); \
    }                                                                          \
    _Pragma("unroll")                                                          \
    for (int p = 0; p < 4; ++p) {                                              \
        A0.h2[p] = __builtin_amdgcn_cvt_pkrtz(w0v[2*p], w0v[2*p+1]);           \
        A1.h2[p] = __builtin_amdgcn_cvt_pkrtz(w1v[2*p], w1v[2*p+1]);           \
    }                                                                          \
} while (0)

// stage-1 MFMAs + G dump for one query, channel-half H (global nt = 2H + n2)
#define DUMP_HALF(Q, H, A0, A1, XV) do {                                       \
    char* gq = g_mem + (Q) * GPITCH;                                           \
    _Pragma("unroll")                                                          \
    for (int n2 = 0; n2 < 2; ++n2) {                                           \
        half8 b;                                                               \
        _Pragma("unroll")                                                      \
        for (int j = 0; j < 8; ++j) b[j] = XV[j][2 * (H) + n2];                \
        f32x4 z = {0.f, 0.f, 0.f, 0.f};                                        \
        f32x4 c0 = __builtin_amdgcn_mfma_f32_16x16x32_f16(A0.v, b, z, 0, 0, 0);\
        f32x4 c1 = __builtin_amdgcn_mfma_f32_16x16x32_f16(A1.v, b, z, 0, 0, 0);\
        const int ic = 16 * n2 + lr;               /* local channel 0..31 */   \
        H4 h0;                                                                 \
        h0.h2[0] = __builtin_amdgcn_cvt_pkrtz(c0[0], c0[1]);                   \
        h0.h2[1] = __builtin_amdgcn_cvt_pkrtz(c0[2], c0[3]);                   \
        *(half4_t*)(gq + 2 * (ic * 28 + 4 * g)) = h0.v;                        \
        if (4 * g < 12) {                                                      \
            H4 h1;                                                             \
            h1.h2[0] = __builtin_amdgcn_cvt_pkrtz(c1[0], c1[1]);               \
            h1.h2[1] = __builtin_amdgcn_cvt_pkrtz(c1[2], c1[3]);               \
            *(half4_t*)(gq + 2 * (ic * 28 + 16 + 4 * g)) = h1.v;               \
        }                                                                      \
    }                                                                          \
} while (0)

// stage-2 K-loop for channel-half H (k_local = kq*448 .. +448, 14 steps)
#define KLOOP(H) do {                                                          \
    const half_t* wr = wrow + (H) * 896;                                       \
    _Pragma("unroll")                                                          \
    for (int s = 0; s < 14; ++s) {                                             \
        half8 a = *(const half8*)(gb + 64 * s + 16 * g);                       \
        half8 b = *(const half8*)(wr + 32 * s);                                \
        if (s & 1) accB = __builtin_amdgcn_mfma_f32_16x16x32_f16(a, b, accB, 0, 0, 0); \
        else       accA = __builtin_amdgcn_mfma_f32_16x16x32_f16(a, b, accA, 0, 0, 0); \
    }                                                                          \
} while (0)

template <int XHALF>
__global__ __launch_bounds__(512, 6) void kpconv(
    const float* __restrict__ q_pts, const float* __restrict__ s_pts,
    const int*   __restrict__ inds,  const float* __restrict__ x,
    const half_t* __restrict__ xh,   const half_t* __restrict__ WT,
    float* __restrict__ out)
{
    // LDS: 29184 + 2048 + 8192 + 4096 = 43520 B -> 3 blocks/CU (24 waves/CU)
    __shared__ __align__(16) char    g_mem[16 * GPITCH];          // half-G [q][i_loc*28+l]
    __shared__ __align__(16) unsigned short idx_lds[2][16][32];   // double-buffered
    __shared__ __align__(16) half4_t nbr_lds[2][16][32];          // double-buffered fp16
    __shared__ __align__(16) f32x4   red[4][64];                  // K-reduction

    const int tid  = threadIdx.x;
    const int lane = tid & 63, wid = tid >> 6;
    const int lr   = lane & 15, g = lane >> 4;
    const int aq   = tid >> 5,  ah = tid & 31;      // phase-A mapping: 16q x 32h
    const int ot   = wid & 3,   kq = wid >> 2;      // stage-2 role: o-tile x K-quarter

    // this lane's two kernel points: l0 = lr, l1 = lr+16 (>=27 -> w=0 via cbias)
    const float kx0 = (float)((lr / 3) % 3 - 1) * KP_S;
    const float ky0 = (float)( lr / 9      - 1) * KP_S;
    const float kz0 = (float)( lr % 3      - 1) * KP_S;
    const int   l1  = lr + 16;
    const float kx1 = (float)((l1 / 3) % 3 - 1) * KP_S;
    const float ky1 = (float)( l1 / 9      - 1) * KP_S;
    const float kz1 = (float)( l1 % 3      - 1) * KP_S;
    const float cbias = (l1 < 27) ? 1.f : -1.f;

    // stage-2 loop-invariant addressing
    const half_t* wrow = WT + (16 * ot + lr) * 1792 + kq * 448 + 8 * g;
    const char*   gb   = g_mem + lr * GPITCH + kq * 896;

    // ---- prologue: phase A for first tile -> buffer 0 ----
    {
        int n   = blockIdx.x * 16 + aq;
        int idx = inds[n * 32 + ah];
        idx_lds[0][aq][ah] = (unsigned short)idx;
        float dx = s_pts[idx * 3 + 0] - q_pts[n * 3 + 0];
        float dy = s_pts[idx * 3 + 1] - q_pts[n * 3 + 1];
        float dz = s_pts[idx * 3 + 2] - q_pts[n * 3 + 2];
        H4 nv;
        nv.h2[0] = __builtin_amdgcn_cvt_pkrtz(dx, dy);
        nv.h2[1] = __builtin_amdgcn_cvt_pkrtz(dz, 0.f);
        nbr_lds[0][aq][ah] = nv.v;
    }
    __syncthreads();

    int cur = 0;
    for (int t = blockIdx.x; t < NTILE; t += NBLK) {
        const int tn  = (t + NBLK < NTILE) ? t + NBLK : t;    // next tile (clamped)
        const int nn  = tn * 16 + aq;

        // ---- S1(h0): gathers + w-frags + channel-half-0 stage-1 ----
        half4_t xv[8], xvB[8];
        ISSUE_XV1(cur, 2 * wid, xv);
        ISSUE_XV1(cur, 2 * wid + 1, xvB);
        const int idxN = inds[nn * 32 + ah];                  // next-tile idx
        H8 A0a, A1a, A0b, A1b;
        COMP_W(2 * wid,     cur, A0a, A1a);
        COMP_W(2 * wid + 1, cur, A0b, A1b);
        DUMP_HALF(2 * wid,     0, A0a, A1a, xv);
        DUMP_HALF(2 * wid + 1, 0, A0b, A1b, xvB);
        BAR_LGKM();                                           // B1: G h0 ready

        // ---- S2(h0) + next-tile nbr chain ----
        const float sx = s_pts[idxN * 3 + 0] - q_pts[nn * 3 + 0];
        const float sy = s_pts[idxN * 3 + 1] - q_pts[nn * 3 + 1];
        const float sz = s_pts[idxN * 3 + 2] - q_pts[nn * 3 + 2];
        f32x4 accA = {0.f, 0.f, 0.f, 0.f}, accB = {0.f, 0.f, 0.f, 0.f};
        KLOOP(0);
        BAR_LGKM();                                           // B2: G h0 readers done

        // ---- S1(h1): channel-half-1 stage-1 (w-frags reused) ----
        DUMP_HALF(2 * wid,     1, A0a, A1a, xv);
        DUMP_HALF(2 * wid + 1, 1, A0b, A1b, xvB);
        idx_lds[cur ^ 1][aq][ah] = (unsigned short)idxN;
        { H4 nv;
          nv.h2[0] = __builtin_amdgcn_cvt_pkrtz(sx, sy);
          nv.h2[1] = __builtin_amdgcn_cvt_pkrtz(sz, 0.f);
          nbr_lds[cur ^ 1][aq][ah] = nv.v; }
        BAR_LGKM();                                           // B3: G h1 + bufs ready

        // ---- S2(h1) + reduce + store ----
        KLOOP(1);
        f32x4 acc = accA + accB;
        if (kq) *(f32x4*)&red[ot][lane] = acc;
        BAR_LGKM();                                           // B4: red ready
        if (!kq) {
            f32x4 p = red[ot][lane];
            const int o = 16 * ot + lr;
            #pragma unroll
            for (int r = 0; r < 4; ++r)
                out[(t * 16 + 4 * g + r) * 64 + o] = acc[r] + p[r];
        }
        cur ^= 1;
    }
}

extern "C" void kernel_launch(void* const* d_in, const int* in_sizes, int n_in,
                              void* d_out, int out_size, void* d_ws, size_t ws_size,
                              hipStream_t stream) {
    const float* q_pts = (const float*)d_in[0];
    const float* s_pts = (const float*)d_in[1];
    const int*   inds  = (const int*)d_in[2];
    const float* x     = (const float*)d_in[3];
    const float* W     = (const float*)d_in[4];
    float* out = (float*)d_out;
    half_t* WT = (half_t*)d_ws;                               // 229376 B
    half_t* xh = (half_t*)((char*)d_ws + WT_BYTES);           // 5120000 B

    build_wt<<<448, 256, 0, stream>>>(W, WT);                 // 448*256 = 114688 exact
    if (ws_size >= (size_t)(WT_BYTES + XH_BYTES)) {
        build_xh<<<2500, 256, 0, stream>>>(x, xh);
        kpconv<1><<<NBLK, 512, 0, stream>>>(q_pts, s_pts, inds, x, xh, WT, out);
    } else {
        kpconv<0><<<NBLK, 512, 0, stream>>>(q_pts, s_pts, inds, x, xh, WT, out);
    }
}